// Round 3
// baseline (85.987 us; speedup 1.0000x reference)
//
#include <hip/hip_runtime.h>

// ---------------------------------------------------------------------------
// ParticleQAEEncoder — packed-fp32 math, R0-verified cross-lane ops.
//
// R1/R2 post-mortem: permlane{16,32}_swap-based lane exchange produced
// bit-identical wrong jet output under two different encodings (builtin and
// forced-distinct-register asm) -> the instruction's lane pairing differs
// from the assumed lane^M model. Abandoned here.  All cross-lane ops below
// are the R0-verified ones (ds_bpermute xor63/xor32, ds_swizzle xor16, DPP
// xor8/4/2/1, __shfl_xor reduction). Packed v_pk_mul/fma_f32 math is kept:
// it was verified by the PASSING met/ele/mu outputs of R1/R2 (same helpers,
// same rotation pattern).
//
// Jet depth-loop budget per wave per depth: 16 bpermute (P1, hoisted above
// the sincos block to hide DS latency) + 32 bpermute (mask 32) + 32
// ds_swizzle (mask 16) = 80 DS ops; all rotations packed (half the FMA
// issues of R0). No LDS allocation, no barriers.
// ---------------------------------------------------------------------------

typedef float v2f __attribute__((ext_vector_type(2)));

// ---- packed fp32 (VOP3P; aligned VGPR pairs) — verified via sim4 R1/R2 ----
__device__ __forceinline__ v2f pk_mul(v2f a, v2f b) {
  v2f d; asm("v_pk_mul_f32 %0, %1, %2" : "=v"(d) : "v"(a), "v"(b)); return d;
}
__device__ __forceinline__ v2f pk_fma(v2f a, v2f b, v2f c) {
  v2f d; asm("v_pk_fma_f32 %0, %1, %2, %3" : "=v"(d) : "v"(a), "v"(b), "v"(c)); return d;
}
__device__ __forceinline__ v2f vbc(float x) { v2f r; r.x = x; r.y = x; return r; }
__device__ __forceinline__ v2f cmulv(v2f a, v2f b) {
  v2f r; r.x = a.x*b.x - a.y*b.y; r.y = a.x*b.y + a.y*b.x; return r;
}
__device__ __forceinline__ v2f cselv(int c, v2f a, v2f b) {
  v2f r; r.x = c ? a.x : b.x; r.y = c ? a.y : b.y; return r;
}

// ---- cross-lane helpers (all R0-verified) ----
template<int CTRL, int ROW, int BANK, bool BC>
__device__ __forceinline__ float dppf(float oldv, float v) {
  return __int_as_float(__builtin_amdgcn_update_dpp(
      __float_as_int(oldv), __float_as_int(v), CTRL, ROW, BANK, BC));
}
__device__ __forceinline__ float xor1f(float v) { return dppf<0xB1, 0xF, 0xF, true>(v, v); }   // quad_perm [1,0,3,2]
__device__ __forceinline__ float xor2f(float v) { return dppf<0x4E, 0xF, 0xF, true>(v, v); }   // quad_perm [2,3,0,1]
__device__ __forceinline__ float xor8f(float v) { return dppf<0x128, 0xF, 0xF, true>(v, v); }  // row_ror:8
__device__ __forceinline__ float xor4f(float v) {
  float t = dppf<0x104, 0xF, 0xA, false>(v, v);   // row_shl:4 into banks 1,3
  return    dppf<0x114, 0xF, 0x5, false>(t, v);   // row_shr:4 into banks 0,2
}
__device__ __forceinline__ float xor16f(float v) {
  return __int_as_float(__builtin_amdgcn_ds_swizzle(__float_as_int(v), 0x401F)); // xor16 in 32-half
}
__device__ __forceinline__ float bpermf(int addr, float v) {
  return __int_as_float(__builtin_amdgcn_ds_bpermute(addr, __float_as_int(v)));
}

// |0>-column of RZ(phi)*RY(pt)*RX(eta)  (applied RX,RY,RZ order)
__device__ __forceinline__ void enc_col(float pt, float eta, float phi,
                                        v2f* A, v2f* Bq) {
  float cx = __cosf(0.5f*eta), sx = __sinf(0.5f*eta);
  float cy = __cosf(0.5f*pt),  sy = __sinf(0.5f*pt);
  float cz = __cosf(0.5f*phi), sz = __sinf(0.5f*phi);
  float u = cy*cx, v = sy*sx;
  float p = sy*cx, q = -cy*sx;
  A->x  = cz*u + sz*v;  A->y  = cz*v - sz*u;
  Bq->x = cz*p - sz*q;  Bq->y = cz*q + sz*p;
}

// lane-wire RY: new = c*self + sg*partner, sg = (lane&M) ? s : -s
#define LANE_RY_SH(K, M, SHUF)                                      \
    { const v2f ccv_ = vbc(c[K]);                                   \
      const float sg_ = (lane & (M)) ? s[K] : -s[K];                \
      const v2f sgv_ = vbc(sg_);                                    \
      _Pragma("unroll")                                             \
      for (int r = 0; r < 16; ++r) {                                \
        v2f o_; o_.x = SHUF(st[r].x); o_.y = SHUF(st[r].y);         \
        st[r] = pk_fma(sgv_, o_, pk_mul(ccv_, st[r]));              \
      } }

// ---------------- jet: one wave per event ----------------
__device__ void jet_sim(const float* __restrict__ xr, const float* __restrict__ jw,
                        float* __restrict__ out, int b, int lane, int B) {
  v2f A[10], Bw[10];
  #pragma unroll
  for (int k = 0; k < 10; ++k)
    enc_col(xr[26+k], xr[36+k], xr[46+k], &A[k], &Bw[k]);

  // lane factor over wires 0..5 (lane bit 5-w)
  v2f f = cselv((lane>>5)&1, Bw[0], A[0]);
  f = cmulv(f, cselv((lane>>4)&1, Bw[1], A[1]));
  f = cmulv(f, cselv((lane>>3)&1, Bw[2], A[2]));
  f = cmulv(f, cselv((lane>>2)&1, Bw[3], A[3]));
  f = cmulv(f, cselv((lane>>1)&1, Bw[4], A[4]));
  f = cmulv(f, cselv( lane    &1, Bw[5], A[5]));

  // product tree over reg bits: r = (b6<<3)|(b7<<2)|(b8<<1)|b9
  v2f st[16];
  {
    v2f h6[2]; h6[0] = cmulv(f, A[6]); h6[1] = cmulv(f, Bw[6]);
    v2f h7[4];
    #pragma unroll
    for (int j = 0; j < 2; ++j) { h7[2*j] = cmulv(h6[j], A[7]); h7[2*j+1] = cmulv(h6[j], Bw[7]); }
    v2f h8[8];
    #pragma unroll
    for (int j = 0; j < 4; ++j) { h8[2*j] = cmulv(h7[j], A[8]); h8[2*j+1] = cmulv(h7[j], Bw[8]); }
    #pragma unroll
    for (int j = 0; j < 8; ++j) { st[2*j] = cmulv(h8[j], A[9]); st[2*j+1] = cmulv(h8[j], Bw[9]); }
  }

  const int a63 = (lane ^ 63) << 2;       // bpermute byte addr for xor63
  const int a32 = (lane ^ 32) << 2;       // bpermute byte addr for xor32
  const int pl  = __popc(lane) & 1;       // parity of latent (all lane bits)

  #pragma unroll
  for (int d = 0; d < 4; ++d) {
    // P1 first: its 16 ds_bpermute latencies hide under the sincos block.
    // flip all latent (lane^63) iff parity(trash)=parity(r) (compile-time)
    #pragma unroll
    for (int r = 0; r < 16; ++r) {
      if (__popc(r) & 1) {
        st[r].x = bpermf(a63, st[r].x);
        st[r].y = bpermf(a63, st[r].y);
      }
    }

    float c[10], s[10];
    #pragma unroll
    for (int k = 0; k < 10; ++k) __sincosf(0.5f * jw[d*10 + k], &s[k], &c[k]);

    // RY on lane wires 0..5 (masks 32,16,8,4,2,1) — R0-verified shuffles
#define SH32(v) bpermf(a32, v)
    LANE_RY_SH(0, 32, SH32)
    LANE_RY_SH(1, 16, xor16f)
#undef SH32
    LANE_RY_SH(2, 8, xor8f)
    LANE_RY_SH(3, 4, xor4f)
    LANE_RY_SH(4, 2, xor2f)
    LANE_RY_SH(5, 1, xor1f)

    // RY on reg wires 6..9 (reg bit 9-k), packed
    #pragma unroll
    for (int k = 6; k < 10; ++k) {
      const v2f cv = vbc(c[k]), sv = vbc(s[k]), nv = vbc(-s[k]);
      const int mr = 1 << (9-k);
      #pragma unroll
      for (int r = 0; r < 16; ++r) {
        if (!(r & mr)) {
          v2f a = st[r], bb = st[r|mr];
          st[r]    = pk_fma(nv, bb, pk_mul(cv, a));   // c*a - s*b
          st[r|mr] = pk_fma(cv, bb, pk_mul(sv, a));   // s*a + c*b
        }
      }
    }

    // P2: flip trash (reg bits, r^15) iff parity(latent lanes) — no shuffles
    #pragma unroll
    for (int r = 0; r < 8; ++r) {
      v2f a = st[r], bb = st[r^15];
      st[r]    = cselv(pl, bb, a);
      st[r^15] = cselv(pl, a, bb);
    }
  }

  // <Z> on trash wires 6..9 = reg bits 3..0; sum over all lanes
  float z0 = 0.f, z1 = 0.f, z2 = 0.f, z3 = 0.f;
  #pragma unroll
  for (int r = 0; r < 16; ++r) {
    float p = st[r].x*st[r].x + st[r].y*st[r].y;
    z0 += (r & 8) ? -p : p;
    z1 += (r & 4) ? -p : p;
    z2 += (r & 2) ? -p : p;
    z3 += (r & 1) ? -p : p;
  }
  #pragma unroll
  for (int j = 1; j <= 32; j <<= 1) {      // R0-verified reduction
    z0 += __shfl_xor(z0, j, 64);
    z1 += __shfl_xor(z1, j, 64);
    z2 += __shfl_xor(z2, j, 64);
    z3 += __shfl_xor(z3, j, 64);
  }
  if (lane == 0) {
    float* o = out + (size_t)5*B + (size_t)b*4;
    o[0] = z0; o[1] = z1; o[2] = z2; o[3] = z3;
  }
}

// ---------------- ele/mu: n=4, 16 amps per thread, depth 1 ----------------
__device__ void sim4(const float* __restrict__ pt, const float* __restrict__ eta,
                     const float* __restrict__ phi, const float* __restrict__ w,
                     float* z_w2, float* z_w3) {
  v2f A[4], Bw[4];
  #pragma unroll
  for (int k = 0; k < 4; ++k)
    enc_col(pt[k], eta[k], phi[k], &A[k], &Bw[k]);

  v2f st[16];
  #pragma unroll
  for (int i = 0; i < 16; ++i) {
    v2f f = cselv((i>>3)&1, Bw[0], A[0]);
    f = cmulv(f, cselv((i>>2)&1, Bw[1], A[1]));
    f = cmulv(f, cselv((i>>1)&1, Bw[2], A[2]));
    f = cmulv(f, cselv( i    &1, Bw[3], A[3]));
    st[i] = f;
  }
  v2f t;
  t = st[1]; st[1] = st[13]; st[13] = t;
  t = st[2]; st[2] = st[14]; st[14] = t;
  t = st[5]; st[5] = st[9];  st[9]  = t;
  t = st[6]; st[6] = st[10]; st[10] = t;
  #pragma unroll
  for (int k = 0; k < 4; ++k) {
    float a5 = 0.5f * w[k];
    float cc = __cosf(a5), ss = __sinf(a5);
    const v2f cv = vbc(cc), sv = vbc(ss), nv = vbc(-ss);
    const int m = 8 >> k;
    #pragma unroll
    for (int i = 0; i < 16; ++i) {
      if (!(i & m)) {
        v2f a = st[i], bb = st[i|m];
        st[i]   = pk_fma(nv, bb, pk_mul(cv, a));
        st[i|m] = pk_fma(cv, bb, pk_mul(sv, a));
      }
    }
  }
  t = st[4]; st[4] = st[7];  st[7]  = t;
  t = st[5]; st[5] = st[6];  st[6]  = t;
  t = st[8]; st[8] = st[11]; st[11] = t;
  t = st[9]; st[9] = st[10]; st[10] = t;

  float z2 = 0.f, z3 = 0.f;
  #pragma unroll
  for (int i = 0; i < 16; ++i) {
    float p = st[i].x*st[i].x + st[i].y*st[i].y;
    z2 += ((i>>1)&1) ? -p : p;
    z3 += ( i    &1) ? -p : p;
  }
  *z_w2 = z2; *z_w3 = z3;
}

__global__ __launch_bounds__(256, 4)
void qae_kernel(const float* __restrict__ x,
                const float* __restrict__ met_w,
                const float* __restrict__ ele_w,
                const float* __restrict__ mu_w,
                const float* __restrict__ jet_w,
                float* __restrict__ out, int B, int jet_blocks) {
  if ((int)blockIdx.x < jet_blocks) {
    int b = blockIdx.x * 4 + (threadIdx.x >> 6);   // one wave per event
    int lane = threadIdx.x & 63;
    if (b < B)
      jet_sim(x + (size_t)b*56, jet_w, out, b, lane, B);
  } else {
    int b = ((int)blockIdx.x - jet_blocks) * 256 + threadIdx.x;
    if (b >= B) return;
    const float* xr = x + (size_t)b*56;
    // ---- met: n=1 analytic ----
    {
      float pt = xr[0], phi = xr[1], mw = met_w[0];
      float cy = __cosf(0.5f*pt),  sy = __sinf(0.5f*pt);
      float cz = __cosf(0.5f*phi), sz = __sinf(0.5f*phi);
      float cw = __cosf(0.5f*mw),  sw = __sinf(0.5f*mw);
      float alre = cz*cy, alim = -sz*cy;
      float bere = cz*sy, beim =  sz*sy;
      float a0re = cw*alre - sw*bere, a0im = cw*alim - sw*beim;
      float a1re = sw*alre + cw*bere, a1im = sw*alim + cw*beim;
      out[b] = (a0re*a0re + a0im*a0im) - (a1re*a1re + a1im*a1im);
    }
    float z2, z3;
    sim4(xr+2,  xr+6,  xr+10, ele_w, &z2, &z3);
    out[B   + b*2 + 0] = z2;  out[B   + b*2 + 1] = z3;
    sim4(xr+14, xr+18, xr+22, mu_w, &z2, &z3);
    out[3*B + b*2 + 0] = z2;  out[3*B + b*2 + 1] = z3;
  }
}

extern "C" void kernel_launch(void* const* d_in, const int* in_sizes, int n_in,
                              void* d_out, int out_size, void* d_ws, size_t ws_size,
                              hipStream_t stream) {
  const float* x     = (const float*)d_in[0];
  const float* met_w = (const float*)d_in[1];
  const float* ele_w = (const float*)d_in[2];
  const float* mu_w  = (const float*)d_in[3];
  const float* jet_w = (const float*)d_in[4];
  float* out = (float*)d_out;
  int B = in_sizes[0] / 56;
  int jet_blocks   = (B + 3) / 4;            // one wave (64 lanes) per event
  int small_blocks = (B + 255) / 256;        // one thread per event
  qae_kernel<<<dim3(jet_blocks + small_blocks), dim3(256), 0, stream>>>(
      x, met_w, ele_w, mu_w, jet_w, out, B, jet_blocks);
}